// Round 2
// baseline (543.365 us; speedup 1.0000x reference)
//
#include <hip/hip_runtime.h>
#include <cstdint>
#include <cstddef>

// Problem constants (PrefixDecoderBlock): B=2, L=2048, d_model=1024, H=16, hd=64, d_ff=4096
#define DM   1024
#define NH   16
#define HD   64
#define DFF  4096
#define BB   2
#define LL   2048
#define MM   (BB*LL)   // 4096 rows total

using short8 = __attribute__((ext_vector_type(8))) short;   // 8 bf16 (4 VGPRs) — MFMA A/B frag
using f32x4  = __attribute__((ext_vector_type(4))) float;   // MFMA C/D frag

// RNE float -> bf16
__device__ __forceinline__ unsigned short f2bf(float f) {
  union { float f; uint32_t u; } v; v.f = f;
  uint32_t u = v.u;
  uint32_t r = (u + 0x7fffu + ((u >> 16) & 1u)) >> 16;
  return (unsigned short)r;
}

// pack 2 f32 -> 2 bf16 (RNE) in one instr; lo halfword = a, hi = b
__device__ __forceinline__ uint32_t cvtpk_bf16(float a, float b) {
  uint32_t r;
  asm("v_cvt_pk_bf16_f32 %0, %1, %2" : "=v"(r) : "v"(a), "v"(b));
  return r;
}

#define GLDS16(gp, lp) \
  __builtin_amdgcn_global_load_lds((const __attribute__((address_space(1))) uint32_t*)(gp), \
                                   (__attribute__((address_space(3))) uint32_t*)(lp), 16, 0, 0)

// ---------------- LayerNorm: fp32 [rows][1024] -> bf16 ----------------
__global__ __launch_bounds__(256) void ln_kernel(const float* __restrict__ x,
                                                 const float* __restrict__ w,
                                                 const float* __restrict__ b,
                                                 unsigned short* __restrict__ out) {
  int row = blockIdx.x, t = threadIdx.x;
  float4 v = ((const float4*)(x + (size_t)row * DM))[t];
  float s  = v.x + v.y + v.z + v.w;
  float sq = v.x*v.x + v.y*v.y + v.z*v.z + v.w*v.w;
  #pragma unroll
  for (int o = 32; o; o >>= 1) { s += __shfl_down(s, o); sq += __shfl_down(sq, o); }
  __shared__ float sh[8];
  if ((t & 63) == 0) { sh[t >> 6] = s; sh[4 + (t >> 6)] = sq; }
  __syncthreads();
  float S  = sh[0] + sh[1] + sh[2] + sh[3];
  float SQ = sh[4] + sh[5] + sh[6] + sh[7];
  float mu  = S * (1.0f / DM);
  float var = SQ * (1.0f / DM) - mu * mu;
  float rs  = rsqrtf(var + 1e-5f);
  float4 wv = ((const float4*)w)[t];
  float4 bv = ((const float4*)b)[t];
  ushort4 o;
  o.x = f2bf((v.x - mu) * rs * wv.x + bv.x);
  o.y = f2bf((v.y - mu) * rs * wv.y + bv.y);
  o.z = f2bf((v.z - mu) * rs * wv.z + bv.z);
  o.w = f2bf((v.w - mu) * rs * wv.w + bv.w);
  ((ushort4*)(out + (size_t)row * DM))[t] = o;
}

// ---------------- GEMM: C[m][n] = A[m][:]·W[n][:] (+bias, epilogues) ----------------
// A: [M][K] bf16 (GLDS16-staged). W: [N][K] fp32 (row-major, K contiguous) — reg-staged
// with in-flight fp32->bf16 conversion (no bf16 weight copy needed in workspace).
// EPI 0: bf16(acc+bias); EPI 1: f32 res+acc+bias; EPI 2: bf16(gelu_exact(acc+bias))
template <int EPI>
__global__ __launch_bounds__(256) void gemm_bt(const unsigned short* __restrict__ A,
                                               const float* __restrict__ Bw,
                                               const float* __restrict__ bias,
                                               const float* __restrict__ res,
                                               void* __restrict__ Cout,
                                               int M, int N, int K) {
  __shared__ unsigned short As[128 * 32];
  __shared__ unsigned short Bs[128 * 32];
  const int t = threadIdx.x;
  const int l = t & 63, lr = l & 15, lg = l >> 4;
  const int w = t >> 6, wm = w >> 1, wn = w & 1;
  const int m0 = blockIdx.y * 128, n0 = blockIdx.x * 128;

  f32x4 acc[4][4];
  #pragma unroll
  for (int mi = 0; mi < 4; ++mi)
    #pragma unroll
    for (int ni = 0; ni < 4; ++ni) acc[mi][ni] = {0.f, 0.f, 0.f, 0.f};

  const unsigned short* Ag = A + (size_t)(m0 + (t >> 2)) * K + (t & 3) * 8;
  char* AsB = (char*)As + t * 16;
  const size_t rstep = (size_t)64 * K;
  // B: thread t stages row (t>>1), 16 k-elements at (t&1)*16
  const float* Bg = Bw + (size_t)(n0 + (t >> 1)) * K + (t & 1) * 16;
  uint32_t* Bd = (uint32_t*)&Bs[(t >> 1) * 32 + (t & 1) * 16];

  for (int k0 = 0; k0 < K; k0 += 32) {
    GLDS16(Ag + k0,         AsB);
    GLDS16(Ag + k0 + rstep, AsB + 4096);
    const float4* bp = (const float4*)(Bg + k0);
    float4 b0 = bp[0], b1 = bp[1], b2 = bp[2], b3 = bp[3];
    uint4 q0, q1;
    q0.x = cvtpk_bf16(b0.x, b0.y); q0.y = cvtpk_bf16(b0.z, b0.w);
    q0.z = cvtpk_bf16(b1.x, b1.y); q0.w = cvtpk_bf16(b1.z, b1.w);
    q1.x = cvtpk_bf16(b2.x, b2.y); q1.y = cvtpk_bf16(b2.z, b2.w);
    q1.z = cvtpk_bf16(b3.x, b3.y); q1.w = cvtpk_bf16(b3.z, b3.w);
    ((uint4*)Bd)[0] = q0;
    ((uint4*)Bd)[1] = q1;
    __syncthreads();
    short8 af[4], bfr[4];
    #pragma unroll
    for (int mi = 0; mi < 4; ++mi)
      af[mi] = *(const short8*)&As[(wm * 64 + mi * 16 + lr) * 32 + lg * 8];
    #pragma unroll
    for (int ni = 0; ni < 4; ++ni)
      bfr[ni] = *(const short8*)&Bs[(wn * 64 + ni * 16 + lr) * 32 + lg * 8];
    #pragma unroll
    for (int mi = 0; mi < 4; ++mi)
      #pragma unroll
      for (int ni = 0; ni < 4; ++ni)
        acc[mi][ni] = __builtin_amdgcn_mfma_f32_16x16x32_bf16(af[mi], bfr[ni], acc[mi][ni], 0, 0, 0);
    __syncthreads();
  }

  #pragma unroll
  for (int mi = 0; mi < 4; ++mi) {
    int row = m0 + wm * 64 + mi * 16 + lg * 4;
    #pragma unroll
    for (int ni = 0; ni < 4; ++ni) {
      int col = n0 + wn * 64 + ni * 16 + lr;
      float bv = bias[col];
      #pragma unroll
      for (int r = 0; r < 4; ++r) {
        float v = acc[mi][ni][r] + bv;
        size_t idx = (size_t)(row + r) * N + col;
        if (EPI == 0) {
          ((unsigned short*)Cout)[idx] = f2bf(v);
        } else if (EPI == 1) {
          ((float*)Cout)[idx] = res[idx] + v;
        } else {
          float g = 0.5f * v * (1.0f + erff(v * 0.70710678118654752f));
          ((unsigned short*)Cout)[idx] = f2bf(g);
        }
      }
    }
  }
}

// ---------------- V transpose: qkv[b][j][2048+h*64+d] -> vt[(b*16+h)*64+d][j] ----------------
__global__ __launch_bounds__(256) void vtrans_kernel(const unsigned short* __restrict__ qkv,
                                                     unsigned short* __restrict__ vt) {
  __shared__ unsigned short tile[64][72];
  int bh = blockIdx.y, b = bh >> 4, h = bh & 15;
  int j0 = blockIdx.x * 64, t = threadIdx.x;
  #pragma unroll
  for (int r = 0; r < 2; ++r) {
    int j = r * 32 + (t >> 3), d0 = (t & 7) * 8;
    short8 v = *(const short8*)(qkv + (size_t)(b * LL + j0 + j) * 3072 + 2048 + h * 64 + d0);
    #pragma unroll
    for (int e = 0; e < 8; ++e) tile[j][d0 + e] = (unsigned short)v[e];
  }
  __syncthreads();
  #pragma unroll
  for (int r = 0; r < 2; ++r) {
    int d = r * 32 + (t >> 3), j = (t & 7) * 8;
    short8 o;
    #pragma unroll
    for (int e = 0; e < 8; ++e) o[e] = (short)tile[j + e][d];
    *(short8*)(vt + (size_t)(bh * 64 + d) * LL + j0 + j) = o;
  }
}

// ---------------- Flash attention with prefix-decoder mask ----------------
// grid: (L/64, B*H), 4 waves; wave w owns q-rows i0+w*16 .. +15.
// allowed(i,j) = (j<m) | (i>=m & j<=i)
__global__ __launch_bounds__(256) void attn_kernel(const unsigned short* __restrict__ qkv,
                                                   const unsigned short* __restrict__ vt,
                                                   const int* __restrict__ prefix,
                                                   unsigned short* __restrict__ ctx) {
  __shared__ unsigned short Plds[4][16][72];   // per-wave P tile, padded rows
  const int t = threadIdx.x, w = t >> 6, l = t & 63, lr = l & 15, lg = l >> 4;
  const int bh = blockIdx.y, b = bh >> 4, h = bh & 15;
  const int i0 = blockIdx.x * 64, iw = i0 + w * 16;
  const int m = *prefix;
  const float scale = 0.125f;  // 1/sqrt(64)

  short8 qf[2];
  {
    const unsigned short* qrow = qkv + (size_t)(b * LL + iw + lr) * 3072 + h * 64;
    qf[0] = *(const short8*)(qrow + lg * 8);
    qf[1] = *(const short8*)(qrow + 32 + lg * 8);
  }
  f32x4 Ot[4];
  #pragma unroll
  for (int dt = 0; dt < 4; ++dt) Ot[dt] = {0.f, 0.f, 0.f, 0.f};
  float mrun[4], lrun[4];
  #pragma unroll
  for (int r = 0; r < 4; ++r) { mrun[r] = -1e30f; lrun[r] = 0.f; }

  const int jmax = (i0 + 64 <= m) ? m : (i0 + 64);
  for (int jt = 0; jt < jmax; jt += 64) {
    f32x4 sc[4];
    #pragma unroll
    for (int nt = 0; nt < 4; ++nt) {
      sc[nt] = {0.f, 0.f, 0.f, 0.f};
      const unsigned short* krow = qkv + (size_t)(b * LL + jt + nt * 16 + lr) * 3072 + DM + h * 64;
      short8 kf0 = *(const short8*)(krow + lg * 8);
      short8 kf1 = *(const short8*)(krow + 32 + lg * 8);
      sc[nt] = __builtin_amdgcn_mfma_f32_16x16x32_bf16(qf[0], kf0, sc[nt], 0, 0, 0);
      sc[nt] = __builtin_amdgcn_mfma_f32_16x16x32_bf16(qf[1], kf1, sc[nt], 0, 0, 0);
    }
    const bool full = (jt + 64 <= m) || (iw >= m && jt + 64 <= iw + 1);
    float pv[4][4];
    float rmax[4] = {-1e30f, -1e30f, -1e30f, -1e30f};
    #pragma unroll
    for (int nt = 0; nt < 4; ++nt) {
      int j = jt + nt * 16 + lr;
      #pragma unroll
      for (int r = 0; r < 4; ++r) {
        float sv = sc[nt][r] * scale;
        if (!full) {
          int i_row = iw + lg * 4 + r;
          bool ok = (j < m) || (i_row >= m && j <= i_row);
          sv = ok ? sv : -1e30f;
        }
        pv[nt][r] = sv;
        rmax[r] = fmaxf(rmax[r], sv);
      }
    }
    #pragma unroll
    for (int r = 0; r < 4; ++r) {
      #pragma unroll
      for (int d = 1; d < 16; d <<= 1) rmax[r] = fmaxf(rmax[r], __shfl_xor(rmax[r], d));
    }
    float alpha[4], rsum[4];
    #pragma unroll
    for (int r = 0; r < 4; ++r) {
      float mnew = fmaxf(mrun[r], rmax[r]);
      alpha[r] = __expf(mrun[r] - mnew);
      mrun[r] = mnew;
      float s = 0.f;
      #pragma unroll
      for (int nt = 0; nt < 4; ++nt) {
        float p = __expf(pv[nt][r] - mnew);
        pv[nt][r] = p;
        s += p;
      }
      rsum[r] = s;
    }
    #pragma unroll
    for (int r = 0; r < 4; ++r) {
      #pragma unroll
      for (int d = 1; d < 16; d <<= 1) rsum[r] += __shfl_xor(rsum[r], d);
      lrun[r] = lrun[r] * alpha[r] + rsum[r];
    }
    #pragma unroll
    for (int dt = 0; dt < 4; ++dt)
      #pragma unroll
      for (int r = 0; r < 4; ++r) Ot[dt][r] *= alpha[r];
    #pragma unroll
    for (int nt = 0; nt < 4; ++nt)
      #pragma unroll
      for (int r = 0; r < 4; ++r)
        Plds[w][lg * 4 + r][nt * 16 + lr] = f2bf(pv[nt][r]);
    short8 paf[2];
    paf[0] = *(const short8*)&Plds[w][lr][lg * 8];
    paf[1] = *(const short8*)&Plds[w][lr][32 + lg * 8];
    #pragma unroll
    for (int dt = 0; dt < 4; ++dt) {
      const unsigned short* vrow = vt + (size_t)(bh * 64 + dt * 16 + lr) * LL + jt;
      short8 vf0 = *(const short8*)(vrow + lg * 8);
      short8 vf1 = *(const short8*)(vrow + 32 + lg * 8);
      Ot[dt] = __builtin_amdgcn_mfma_f32_16x16x32_bf16(paf[0], vf0, Ot[dt], 0, 0, 0);
      Ot[dt] = __builtin_amdgcn_mfma_f32_16x16x32_bf16(paf[1], vf1, Ot[dt], 0, 0, 0);
    }
  }
  #pragma unroll
  for (int r = 0; r < 4; ++r) {
    float inv = 1.0f / lrun[r];
    size_t row = (size_t)(b * LL + iw + lg * 4 + r);
    #pragma unroll
    for (int dt = 0; dt < 4; ++dt)
      ctx[row * DM + h * 64 + dt * 16 + lr] = f2bf(Ot[dt][r] * inv);
  }
}

// ---------------- launch ----------------
// Workspace layout (56 MB total; lifetimes disjoint where aliased):
//   [0,  8M)  slab : h1 (LN1->qkvGEMM), ctx (attn->outproj), h2 (LN2->fc1GEMM)
//   [8, 24M)  x2 (fp32, outproj->end); vt aliases [8,16.4M) (vtrans->attn, dead before x2)
//   [24,56M)  qkv [24,49.2M) (qkvGEMM->attn); ffmid aliases [24,56M) (fc1GEMM->final)
extern "C" void kernel_launch(void* const* d_in, const int* in_sizes, int n_in,
                              void* d_out, int out_size, void* d_ws, size_t ws_size,
                              hipStream_t stream) {
  const float* x        = (const float*)d_in[0];
  const float* ln1_w    = (const float*)d_in[1];
  const float* ln1_b    = (const float*)d_in[2];
  const float* in_proj_w= (const float*)d_in[3];
  const float* in_proj_b= (const float*)d_in[4];
  const float* out_w    = (const float*)d_in[5];
  const float* out_b    = (const float*)d_in[6];
  const float* ln2_w    = (const float*)d_in[7];
  const float* ln2_b    = (const float*)d_in[8];
  const float* fc1_w    = (const float*)d_in[9];
  const float* fc1_b    = (const float*)d_in[10];
  const float* fc2_w    = (const float*)d_in[11];
  const float* fc2_b    = (const float*)d_in[12];
  const int*   prefix   = (const int*)d_in[13];
  float* outp = (float*)d_out;

  char* ws = (char*)d_ws;
  unsigned short* slab  = (unsigned short*)ws;                          // 8 MB
  float*          x2    = (float*)(ws + ((size_t)8 << 20));             // 16 MB
  unsigned short* vtb   = (unsigned short*)(ws + ((size_t)8 << 20));    // alias (8.4 MB)
  unsigned short* qkv   = (unsigned short*)(ws + ((size_t)24 << 20));   // 25.2 MB
  unsigned short* ffmid = qkv;                                          // alias (33.5 MB)

  // h1 = LN1(x)
  ln_kernel<<<MM, 256, 0, stream>>>(x, ln1_w, ln1_b, slab);
  // qkv = h1 @ in_proj_w^T + b   (weights converted fp32->bf16 in-kernel)
  gemm_bt<0><<<dim3(3072 / 128, MM / 128), 256, 0, stream>>>(slab, in_proj_w, in_proj_b, nullptr, qkv, MM, 3072, 1024);
  // vt = V^T per (b,h)
  vtrans_kernel<<<dim3(LL / 64, BB * NH), 256, 0, stream>>>(qkv, vtb);
  // ctx = prefix-masked attention (into slab; h1 dead)
  attn_kernel<<<dim3(LL / 64, BB * NH), 256, 0, stream>>>(qkv, vtb, prefix, slab);
  // x2 = x + ctx @ out_w^T + out_b   (x2 overwrites dead vt alias)
  gemm_bt<1><<<dim3(1024 / 128, MM / 128), 256, 0, stream>>>(slab, out_w, out_b, x, x2, MM, 1024, 1024);
  // h2 = LN2(x2) (into slab; ctx dead)
  ln_kernel<<<MM, 256, 0, stream>>>(x2, ln2_w, ln2_b, slab);
  // ffmid = gelu(h2 @ fc1_w^T + fc1_b)  (overwrites dead qkv region)
  gemm_bt<2><<<dim3(4096 / 128, MM / 128), 256, 0, stream>>>(slab, fc1_w, fc1_b, nullptr, ffmid, MM, 4096, 1024);
  // out = x2 + ffmid @ fc2_w^T + fc2_b
  gemm_bt<1><<<dim3(1024 / 128, MM / 128), 256, 0, stream>>>(ffmid, fc2_w, fc2_b, x2, outp, MM, 1024, 4096);
}

// Round 3
// 427.444 us; speedup vs baseline: 1.2712x; 1.2712x over previous
//
#include <hip/hip_runtime.h>
#include <cstdint>
#include <cstddef>

// Problem constants (PrefixDecoderBlock): B=2, L=2048, d_model=1024, H=16, hd=64, d_ff=4096
#define DM   1024
#define NH   16
#define HD   64
#define DFF  4096
#define BB   2
#define LL   2048
#define MM   (BB*LL)   // 4096 rows total

using short8 = __attribute__((ext_vector_type(8))) short;   // 8 bf16 (4 VGPRs) — MFMA A/B frag
using f32x4  = __attribute__((ext_vector_type(4))) float;   // MFMA C/D frag

// RNE float -> bf16
__device__ __forceinline__ unsigned short f2bf(float f) {
  union { float f; uint32_t u; } v; v.f = f;
  uint32_t u = v.u;
  uint32_t r = (u + 0x7fffu + ((u >> 16) & 1u)) >> 16;
  return (unsigned short)r;
}

// pack 2 f32 -> 2 bf16 (RNE) in one instr; lo halfword = a, hi = b
__device__ __forceinline__ uint32_t cvtpk_bf16(float a, float b) {
  uint32_t r;
  asm("v_cvt_pk_bf16_f32 %0, %1, %2" : "=v"(r) : "v"(a), "v"(b));
  return r;
}

#define GLDS16(gp, lp) \
  __builtin_amdgcn_global_load_lds((const __attribute__((address_space(1))) uint32_t*)(gp), \
                                   (__attribute__((address_space(3))) uint32_t*)(lp), 16, 0, 0)

// ---------------- LayerNorm: fp32 [rows][1024] -> bf16 ----------------
__global__ __launch_bounds__(256) void ln_kernel(const float* __restrict__ x,
                                                 const float* __restrict__ w,
                                                 const float* __restrict__ b,
                                                 unsigned short* __restrict__ out) {
  int row = blockIdx.x, t = threadIdx.x;
  float4 v = ((const float4*)(x + (size_t)row * DM))[t];
  float s  = v.x + v.y + v.z + v.w;
  float sq = v.x*v.x + v.y*v.y + v.z*v.z + v.w*v.w;
  #pragma unroll
  for (int o = 32; o; o >>= 1) { s += __shfl_down(s, o); sq += __shfl_down(sq, o); }
  __shared__ float sh[8];
  if ((t & 63) == 0) { sh[t >> 6] = s; sh[4 + (t >> 6)] = sq; }
  __syncthreads();
  float S  = sh[0] + sh[1] + sh[2] + sh[3];
  float SQ = sh[4] + sh[5] + sh[6] + sh[7];
  float mu  = S * (1.0f / DM);
  float var = SQ * (1.0f / DM) - mu * mu;
  float rs  = rsqrtf(var + 1e-5f);
  float4 wv = ((const float4*)w)[t];
  float4 bv = ((const float4*)b)[t];
  ushort4 o;
  o.x = f2bf((v.x - mu) * rs * wv.x + bv.x);
  o.y = f2bf((v.y - mu) * rs * wv.y + bv.y);
  o.z = f2bf((v.z - mu) * rs * wv.z + bv.z);
  o.w = f2bf((v.w - mu) * rs * wv.w + bv.w);
  ((ushort4*)(out + (size_t)row * DM))[t] = o;
}

// ---------------- GEMM: C[m][n] = A[m][:]·W[n][:] (+bias, epilogues) ----------------
// A: [M][K] bf16 (GLDS16-staged). W: [N][K] fp32 (row-major, K contiguous) — reg-staged
// with in-flight fp32->bf16 conversion (no bf16 weight copy needed in workspace).
// EPI 0: bf16(acc+bias); EPI 1: f32 res+acc+bias; EPI 2: bf16(gelu_exact(acc+bias))
template <int EPI>
__global__ __launch_bounds__(256) void gemm_bt(const unsigned short* __restrict__ A,
                                               const float* __restrict__ Bw,
                                               const float* __restrict__ bias,
                                               const float* __restrict__ res,
                                               void* __restrict__ Cout,
                                               int M, int N, int K) {
  __shared__ unsigned short As[128 * 32];
  __shared__ unsigned short Bs[128 * 32];
  const int t = threadIdx.x;
  const int l = t & 63, lr = l & 15, lg = l >> 4;
  const int w = t >> 6, wm = w >> 1, wn = w & 1;
  const int m0 = blockIdx.y * 128, n0 = blockIdx.x * 128;

  f32x4 acc[4][4];
  #pragma unroll
  for (int mi = 0; mi < 4; ++mi)
    #pragma unroll
    for (int ni = 0; ni < 4; ++ni) acc[mi][ni] = {0.f, 0.f, 0.f, 0.f};

  const unsigned short* Ag = A + (size_t)(m0 + (t >> 2)) * K + (t & 3) * 8;
  char* AsB = (char*)As + t * 16;
  const size_t rstep = (size_t)64 * K;
  // B: thread t stages row (t>>1), 16 k-elements at (t&1)*16
  const float* Bg = Bw + (size_t)(n0 + (t >> 1)) * K + (t & 1) * 16;
  uint32_t* Bd = (uint32_t*)&Bs[(t >> 1) * 32 + (t & 1) * 16];

  for (int k0 = 0; k0 < K; k0 += 32) {
    GLDS16(Ag + k0,         AsB);
    GLDS16(Ag + k0 + rstep, AsB + 4096);
    const float4* bp = (const float4*)(Bg + k0);
    float4 b0 = bp[0], b1 = bp[1], b2 = bp[2], b3 = bp[3];
    uint4 q0, q1;
    q0.x = cvtpk_bf16(b0.x, b0.y); q0.y = cvtpk_bf16(b0.z, b0.w);
    q0.z = cvtpk_bf16(b1.x, b1.y); q0.w = cvtpk_bf16(b1.z, b1.w);
    q1.x = cvtpk_bf16(b2.x, b2.y); q1.y = cvtpk_bf16(b2.z, b2.w);
    q1.z = cvtpk_bf16(b3.x, b3.y); q1.w = cvtpk_bf16(b3.z, b3.w);
    ((uint4*)Bd)[0] = q0;
    ((uint4*)Bd)[1] = q1;
    __syncthreads();
    short8 af[4], bfr[4];
    #pragma unroll
    for (int mi = 0; mi < 4; ++mi)
      af[mi] = *(const short8*)&As[(wm * 64 + mi * 16 + lr) * 32 + lg * 8];
    #pragma unroll
    for (int ni = 0; ni < 4; ++ni)
      bfr[ni] = *(const short8*)&Bs[(wn * 64 + ni * 16 + lr) * 32 + lg * 8];
    #pragma unroll
    for (int mi = 0; mi < 4; ++mi)
      #pragma unroll
      for (int ni = 0; ni < 4; ++ni)
        acc[mi][ni] = __builtin_amdgcn_mfma_f32_16x16x32_bf16(af[mi], bfr[ni], acc[mi][ni], 0, 0, 0);
    __syncthreads();
  }

  #pragma unroll
  for (int mi = 0; mi < 4; ++mi) {
    int row = m0 + wm * 64 + mi * 16 + lg * 4;
    #pragma unroll
    for (int ni = 0; ni < 4; ++ni) {
      int col = n0 + wn * 64 + ni * 16 + lr;
      float bv = bias[col];
      #pragma unroll
      for (int r = 0; r < 4; ++r) {
        float v = acc[mi][ni][r] + bv;
        size_t idx = (size_t)(row + r) * N + col;
        if (EPI == 0) {
          ((unsigned short*)Cout)[idx] = f2bf(v);
        } else if (EPI == 1) {
          ((float*)Cout)[idx] = res[idx] + v;
        } else {
          float g = 0.5f * v * (1.0f + erff(v * 0.70710678118654752f));
          ((unsigned short*)Cout)[idx] = f2bf(g);
        }
      }
    }
  }
}

// ---------------- V transpose: qkv[b][j][2048+h*64+d] -> vt[(b*16+h)*64+d][j] ----------------
__global__ __launch_bounds__(256) void vtrans_kernel(const unsigned short* __restrict__ qkv,
                                                     unsigned short* __restrict__ vt) {
  __shared__ unsigned short tile[64][72];
  int bh = blockIdx.y, b = bh >> 4, h = bh & 15;
  int j0 = blockIdx.x * 64, t = threadIdx.x;
  #pragma unroll
  for (int r = 0; r < 2; ++r) {
    int j = r * 32 + (t >> 3), d0 = (t & 7) * 8;
    short8 v = *(const short8*)(qkv + (size_t)(b * LL + j0 + j) * 3072 + 2048 + h * 64 + d0);
    #pragma unroll
    for (int e = 0; e < 8; ++e) tile[j][d0 + e] = (unsigned short)v[e];
  }
  __syncthreads();
  #pragma unroll
  for (int r = 0; r < 2; ++r) {
    int d = r * 32 + (t >> 3), j = (t & 7) * 8;
    short8 o;
    #pragma unroll
    for (int e = 0; e < 8; ++e) o[e] = (short)tile[j + e][d];
    *(short8*)(vt + (size_t)(bh * 64 + d) * LL + j0 + j) = o;
  }
}

// ---------------- Flash attention with prefix-decoder mask ----------------
// grid: (L/64, B*H), 4 waves; wave w owns q-rows i0+w*16 .. +15.
// allowed(i,j) = (j<m) | (i>=m & j<=i)
// K and V^T tiles (64x64) are LDS-staged cooperatively per j-chunk via global_load_lds
// with XOR-swizzled source (seg ^= row&7) + matching swizzled ds_read (G21 both-sides).
__global__ __launch_bounds__(256) void attn_kernel(const unsigned short* __restrict__ qkv,
                                                   const unsigned short* __restrict__ vt,
                                                   const int* __restrict__ prefix,
                                                   unsigned short* __restrict__ ctx) {
  __shared__ unsigned short Ks[64 * 64];       // [j][d], swizzled
  __shared__ unsigned short Vs[64 * 64];       // [d][j], swizzled
  __shared__ unsigned short Plds[4][16][72];   // per-wave P tile, padded rows
  const int t = threadIdx.x, w = t >> 6, l = t & 63, lr = l & 15, lg = l >> 4;
  const int bh = blockIdx.y, b = bh >> 4, h = bh & 15;
  const int i0 = blockIdx.x * 64, iw = i0 + w * 16;
  const int m = *prefix;
  const float scale = 0.125f;  // 1/sqrt(64)

  // staging: thread t handles tile row r0=t>>3, 16B segment s0=t&7, source pre-swizzled
  const int r0 = t >> 3, s0 = t & 7, swz = s0 ^ (r0 & 7);
  const unsigned short* Kg0 = qkv + (size_t)(b * LL + r0) * 3072 + DM + h * 64 + swz * 8;
  const unsigned short* Vg0 = vt + (size_t)(bh * 64 + r0) * LL + swz * 8;
  char* Kd = (char*)Ks + t * 16;
  char* Vd = (char*)Vs + t * 16;
  // read-side swizzled segment indices (row&7 == lr&7 for all fragment rows)
  const int rs = lr & 7;
  const int segA = (lg ^ rs) * 8;        // k-elements 0..31 half
  const int segB = ((lg + 4) ^ rs) * 8;  // k-elements 32..63 half

  short8 qf[2];
  {
    const unsigned short* qrow = qkv + (size_t)(b * LL + iw + lr) * 3072 + h * 64;
    qf[0] = *(const short8*)(qrow + lg * 8);
    qf[1] = *(const short8*)(qrow + 32 + lg * 8);
  }
  f32x4 Ot[4];
  #pragma unroll
  for (int dt = 0; dt < 4; ++dt) Ot[dt] = {0.f, 0.f, 0.f, 0.f};
  float mrun[4], lrun[4];
  #pragma unroll
  for (int r = 0; r < 4; ++r) { mrun[r] = -1e30f; lrun[r] = 0.f; }

  const int jmax = (i0 + 64 <= m) ? m : (i0 + 64);
  for (int jt = 0; jt < jmax; jt += 64) {
    // cooperative stage: K rows jt..jt+63 (cols h*64..+63), V^T rows d=0..63 (cols jt..+63)
    GLDS16(Kg0 + (size_t)jt * 3072,        Kd);
    GLDS16(Kg0 + (size_t)(jt + 32) * 3072, Kd + 4096);
    GLDS16(Vg0 + jt,                       Vd);
    GLDS16(Vg0 + jt + (size_t)32 * LL,     Vd + 4096);
    __syncthreads();

    f32x4 sc[4];
    #pragma unroll
    for (int nt = 0; nt < 4; ++nt) {
      sc[nt] = {0.f, 0.f, 0.f, 0.f};
      const int row = nt * 16 + lr;
      short8 kf0 = *(const short8*)&Ks[row * 64 + segA];
      short8 kf1 = *(const short8*)&Ks[row * 64 + segB];
      sc[nt] = __builtin_amdgcn_mfma_f32_16x16x32_bf16(qf[0], kf0, sc[nt], 0, 0, 0);
      sc[nt] = __builtin_amdgcn_mfma_f32_16x16x32_bf16(qf[1], kf1, sc[nt], 0, 0, 0);
    }
    const bool full = (jt + 64 <= m) || (iw >= m && jt + 64 <= iw + 1);
    float pv[4][4];
    float rmax[4] = {-1e30f, -1e30f, -1e30f, -1e30f};
    #pragma unroll
    for (int nt = 0; nt < 4; ++nt) {
      int j = jt + nt * 16 + lr;
      #pragma unroll
      for (int r = 0; r < 4; ++r) {
        float sv = sc[nt][r] * scale;
        if (!full) {
          int i_row = iw + lg * 4 + r;
          bool ok = (j < m) || (i_row >= m && j <= i_row);
          sv = ok ? sv : -1e30f;
        }
        pv[nt][r] = sv;
        rmax[r] = fmaxf(rmax[r], sv);
      }
    }
    #pragma unroll
    for (int r = 0; r < 4; ++r) {
      #pragma unroll
      for (int d = 1; d < 16; d <<= 1) rmax[r] = fmaxf(rmax[r], __shfl_xor(rmax[r], d));
    }
    float alpha[4], rsum[4];
    #pragma unroll
    for (int r = 0; r < 4; ++r) {
      float mnew = fmaxf(mrun[r], rmax[r]);
      alpha[r] = __expf(mrun[r] - mnew);
      mrun[r] = mnew;
      float s = 0.f;
      #pragma unroll
      for (int nt = 0; nt < 4; ++nt) {
        float p = __expf(pv[nt][r] - mnew);
        pv[nt][r] = p;
        s += p;
      }
      rsum[r] = s;
    }
    #pragma unroll
    for (int r = 0; r < 4; ++r) {
      #pragma unroll
      for (int d = 1; d < 16; d <<= 1) rsum[r] += __shfl_xor(rsum[r], d);
      lrun[r] = lrun[r] * alpha[r] + rsum[r];
    }
    #pragma unroll
    for (int dt = 0; dt < 4; ++dt)
      #pragma unroll
      for (int r = 0; r < 4; ++r) Ot[dt][r] *= alpha[r];
    #pragma unroll
    for (int nt = 0; nt < 4; ++nt)
      #pragma unroll
      for (int r = 0; r < 4; ++r)
        Plds[w][lg * 4 + r][nt * 16 + lr] = f2bf(pv[nt][r]);
    short8 paf[2];
    paf[0] = *(const short8*)&Plds[w][lr][lg * 8];
    paf[1] = *(const short8*)&Plds[w][lr][32 + lg * 8];
    #pragma unroll
    for (int dt = 0; dt < 4; ++dt) {
      const int row = dt * 16 + lr;
      short8 vf0 = *(const short8*)&Vs[row * 64 + segA];
      short8 vf1 = *(const short8*)&Vs[row * 64 + segB];
      Ot[dt] = __builtin_amdgcn_mfma_f32_16x16x32_bf16(paf[0], vf0, Ot[dt], 0, 0, 0);
      Ot[dt] = __builtin_amdgcn_mfma_f32_16x16x32_bf16(paf[1], vf1, Ot[dt], 0, 0, 0);
    }
    __syncthreads();
  }
  #pragma unroll
  for (int r = 0; r < 4; ++r) {
    float inv = 1.0f / lrun[r];
    size_t row = (size_t)(b * LL + iw + lg * 4 + r);
    #pragma unroll
    for (int dt = 0; dt < 4; ++dt)
      ctx[row * DM + h * 64 + dt * 16 + lr] = f2bf(Ot[dt][r] * inv);
  }
}

// ---------------- launch ----------------
// Workspace layout (56 MB total; lifetimes disjoint where aliased):
//   [0,  8M)  slab : h1 (LN1->qkvGEMM), ctx (attn->outproj), h2 (LN2->fc1GEMM)
//   [8, 24M)  x2 (fp32, outproj->end); vt aliases [8,16.4M) (vtrans->attn, dead before x2)
//   [24,56M)  qkv [24,49.2M) (qkvGEMM->attn); ffmid aliases [24,56M) (fc1GEMM->final)
extern "C" void kernel_launch(void* const* d_in, const int* in_sizes, int n_in,
                              void* d_out, int out_size, void* d_ws, size_t ws_size,
                              hipStream_t stream) {
  const float* x        = (const float*)d_in[0];
  const float* ln1_w    = (const float*)d_in[1];
  const float* ln1_b    = (const float*)d_in[2];
  const float* in_proj_w= (const float*)d_in[3];
  const float* in_proj_b= (const float*)d_in[4];
  const float* out_w    = (const float*)d_in[5];
  const float* out_b    = (const float*)d_in[6];
  const float* ln2_w    = (const float*)d_in[7];
  const float* ln2_b    = (const float*)d_in[8];
  const float* fc1_w    = (const float*)d_in[9];
  const float* fc1_b    = (const float*)d_in[10];
  const float* fc2_w    = (const float*)d_in[11];
  const float* fc2_b    = (const float*)d_in[12];
  const int*   prefix   = (const int*)d_in[13];
  float* outp = (float*)d_out;

  char* ws = (char*)d_ws;
  unsigned short* slab  = (unsigned short*)ws;                          // 8 MB
  float*          x2    = (float*)(ws + ((size_t)8 << 20));             // 16 MB
  unsigned short* vtb   = (unsigned short*)(ws + ((size_t)8 << 20));    // alias (8.4 MB)
  unsigned short* qkv   = (unsigned short*)(ws + ((size_t)24 << 20));   // 25.2 MB
  unsigned short* ffmid = qkv;                                          // alias (33.5 MB)

  // h1 = LN1(x)
  ln_kernel<<<MM, 256, 0, stream>>>(x, ln1_w, ln1_b, slab);
  // qkv = h1 @ in_proj_w^T + b   (weights converted fp32->bf16 in-kernel)
  gemm_bt<0><<<dim3(3072 / 128, MM / 128), 256, 0, stream>>>(slab, in_proj_w, in_proj_b, nullptr, qkv, MM, 3072, 1024);
  // vt = V^T per (b,h)
  vtrans_kernel<<<dim3(LL / 64, BB * NH), 256, 0, stream>>>(qkv, vtb);
  // ctx = prefix-masked attention (into slab; h1 dead)
  attn_kernel<<<dim3(LL / 64, BB * NH), 256, 0, stream>>>(qkv, vtb, prefix, slab);
  // x2 = x + ctx @ out_w^T + out_b   (x2 overwrites dead vt alias)
  gemm_bt<1><<<dim3(1024 / 128, MM / 128), 256, 0, stream>>>(slab, out_w, out_b, x, x2, MM, 1024, 1024);
  // h2 = LN2(x2) (into slab; ctx dead)
  ln_kernel<<<MM, 256, 0, stream>>>(x2, ln2_w, ln2_b, slab);
  // ffmid = gelu(h2 @ fc1_w^T + fc1_b)  (overwrites dead qkv region)
  gemm_bt<2><<<dim3(4096 / 128, MM / 128), 256, 0, stream>>>(slab, fc1_w, fc1_b, nullptr, ffmid, MM, 4096, 1024);
  // out = x2 + ffmid @ fc2_w^T + fc2_b
  gemm_bt<1><<<dim3(1024 / 128, MM / 128), 256, 0, stream>>>(ffmid, fc2_w, fc2_b, x2, outp, MM, 1024, 4096);
}